// Round 2
// baseline (3569.350 us; speedup 1.0000x reference)
//
#include <hip/hip_runtime.h>
#include <math.h>
#include <float.h>

#define N_ROWS 65536
#define K_CODES 1024
#define C_DIM 64
#define BLK 256
#define RB 64                     // rows per block
#define CHUNK 128                 // codes staged per LDS chunk
#define NCHUNK (K_CODES / CHUNK)  // 8
#define R 4                       // rows per thread
#define KC 8                      // codes per thread per chunk
#define P4 17                     // LDS pitch in float4 units (68 floats, odd f4 stride)

// d_out layout (float32), outputs concatenated in return order:
// [loss(1)][quantized_st(N*C)][perplexity(1)][indices(N)][avg_probs(K)]
#define OUT_LOSS 0
#define OUT_Q 1
#define OUT_PPL (1 + N_ROWS * C_DIM)     // 4194305
#define OUT_IDX (OUT_PPL + 1)            // 4194306
#define OUT_AVG (OUT_IDX + N_ROWS)       // 4259842

// d_ws layout (4-byte units)
#define WS_HIST 0          // uint[1024]
#define WS_EE 1024         // float[1024]
#define WS_LOSSP 2048      // float[1024] per-block loss partials

// Kernel A: zero histogram, precompute ||e_k||^2
__global__ void vq_prep(const float* __restrict__ emb,
                        float* __restrict__ ee,
                        unsigned* __restrict__ hist) {
    int k = blockIdx.x * blockDim.x + threadIdx.x;
    if (k < K_CODES) {
        hist[k] = 0u;
        const float4* ev = (const float4*)(emb + (size_t)k * C_DIM);
        float s0 = 0.f, s1 = 0.f, s2 = 0.f, s3 = 0.f;
#pragma unroll
        for (int i = 0; i < 16; ++i) {
            float4 e = ev[i];
            s0 = fmaf(e.x, e.x, s0);
            s1 = fmaf(e.y, e.y, s1);
            s2 = fmaf(e.z, e.z, s2);
            s3 = fmaf(e.w, e.w, s3);
        }
        ee[k] = (s0 + s1) + (s2 + s3);
    }
}

// Kernel B (fused): distances + argmin + indices + histogram + quantized_st + loss partial
__global__ __launch_bounds__(BLK, 2) void vq_main(
    const float* __restrict__ x, const float* __restrict__ emb,
    const float* __restrict__ ee, unsigned* __restrict__ hist,
    float* __restrict__ lossp, float* __restrict__ out) {
    __shared__ __align__(16) float sX[RB * P4 * 4];      // 64 rows, pitch 68 -> 17 KB
    __shared__ __align__(16) float sE[CHUNK * P4 * 4];   // 128 codes, pitch 68 -> 34 KB
    __shared__ float sEE[CHUNK];
    __shared__ int sIdx[RB];
    __shared__ unsigned sHist[K_CODES];
    __shared__ float sRed[BLK / 64];

    const int t = threadIdx.x;
    const int tx = t & 15;        // code group
    const int ty = t >> 4;        // row group
    const int rowbase = blockIdx.x * RB;

    float4* sX4 = (float4*)sX;
    float4* sE4 = (float4*)sE;

    // zero LDS hist + stage x-tile (64 rows, coalesced f4, padded pitch)
    for (int k = t; k < K_CODES; k += BLK) sHist[k] = 0u;
    {
        const float4* gx = (const float4*)x + (size_t)rowbase * (C_DIM / 4);
#pragma unroll
        for (int i = 0; i < (RB * C_DIM / 4) / BLK; ++i) {  // 4 f4/thread
            int p = t + i * BLK;
            sX4[(p >> 4) * P4 + (p & 15)] = gx[p];
        }
    }

    float best[R];
    int bidx[R];
#pragma unroll
    for (int i = 0; i < R; ++i) { best[i] = FLT_MAX; bidx[i] = 0; }

    for (int ch = 0; ch < NCHUNK; ++ch) {
        __syncthreads();
        {
            const float4* ge = (const float4*)emb + (size_t)ch * CHUNK * (C_DIM / 4);
#pragma unroll
            for (int i = 0; i < (CHUNK * C_DIM / 4) / BLK; ++i) {  // 8 f4/thread
                int p = t + i * BLK;
                sE4[(p >> 4) * P4 + (p & 15)] = ge[p];
            }
            if (t < CHUNK) sEE[t] = ee[ch * CHUNK + t];
        }
        __syncthreads();

        // 4x8 register tile, float4 partial accumulators (preserves the exact
        // per-dot summation order of the previously-verified kernel:
        // 4 partials over c%4 classes, then (d0+d1)+(d2+d3))
        float4 acc[R][KC];
#pragma unroll
        for (int i = 0; i < R; ++i)
#pragma unroll
            for (int j = 0; j < KC; ++j) acc[i][j] = make_float4(0.f, 0.f, 0.f, 0.f);

#pragma unroll
        for (int c4 = 0; c4 < C_DIM / 4; ++c4) {
            float4 xa[R], eb[KC];
#pragma unroll
            for (int i = 0; i < R; ++i) xa[i] = sX4[(ty * R + i) * P4 + c4];
#pragma unroll
            for (int j = 0; j < KC; ++j) eb[j] = sE4[(j * 16 + tx) * P4 + c4];
#pragma unroll
            for (int i = 0; i < R; ++i)
#pragma unroll
                for (int j = 0; j < KC; ++j) {
                    acc[i][j].x = fmaf(xa[i].x, eb[j].x, acc[i][j].x);
                    acc[i][j].y = fmaf(xa[i].y, eb[j].y, acc[i][j].y);
                    acc[i][j].z = fmaf(xa[i].z, eb[j].z, acc[i][j].z);
                    acc[i][j].w = fmaf(xa[i].w, eb[j].w, acc[i][j].w);
                }
        }

#pragma unroll
        for (int j = 0; j < KC; ++j) {
            float eek = sEE[j * 16 + tx];
            int code = ch * CHUNK + j * 16 + tx;
#pragma unroll
            for (int i = 0; i < R; ++i) {
                float dot = (acc[i][j].x + acc[i][j].y) + (acc[i][j].z + acc[i][j].w);
                float s = fmaf(-2.0f, dot, eek);       // ||e||^2 - 2 x.e
                if (s < best[i]) { best[i] = s; bidx[i] = code; }  // strict <: first-min
            }
        }
    }

    // cross-tx argmin reduce (16 lanes per row group, lexicographic (score, idx))
#pragma unroll
    for (int i = 0; i < R; ++i) {
        float b = best[i];
        int bi = bidx[i];
#pragma unroll
        for (int m = 8; m >= 1; m >>= 1) {
            float ob = __shfl_xor(b, m, 64);
            int oi = __shfl_xor(bi, m, 64);
            if (ob < b || (ob == b && oi < bi)) { b = ob; bi = oi; }
        }
        if (tx == 0) sIdx[ty * R + i] = bi;
    }
    __syncthreads();

    // indices out + LDS histogram
    if (t < RB) {
        int bi = sIdx[t];
        out[OUT_IDX + rowbase + t] = (float)bi;
        atomicAdd(&sHist[bi], 1u);
    }
    __syncthreads();
    for (int k = t; k < K_CODES; k += BLK) {
        unsigned c = sHist[k];
        if (c) atomicAdd(&hist[k], c);
    }

    // epilogue: quantized_st + loss partial (wave-uniform row -> coalesced)
    const int col = t & 63;
    const int rg = t >> 6;
    float lsum = 0.f;
#pragma unroll
    for (int it = 0; it < RB / 4; ++it) {
        int rl = it * 4 + rg;
        int bi = sIdx[rl];                       // uniform in wave -> broadcast
        float xv = sX[rl * (P4 * 4) + col];
        float qv = emb[(size_t)bi * C_DIM + col];
        float d = qv - xv;
        out[OUT_Q + (size_t)(rowbase + rl) * C_DIM + col] = xv + d;  // straight-through
        lsum = fmaf(d, d, lsum);
    }
#pragma unroll
    for (int o = 32; o > 0; o >>= 1) lsum += __shfl_down(lsum, o, 64);
    if ((t & 63) == 0) sRed[t >> 6] = lsum;
    __syncthreads();
    if (t == 0) lossp[blockIdx.x] = (sRed[0] + sRed[1]) + (sRed[2] + sRed[3]);
}

// Kernel C: avg_probs, perplexity, loss finalization (parallel reductions)
__global__ void vq_final(const unsigned* __restrict__ hist,
                         const float* __restrict__ lossp,
                         float* __restrict__ out) {
    __shared__ float sP[K_CODES];
    __shared__ float sL[K_CODES];
    const int t = threadIdx.x;
    float p = (float)hist[t] * (1.0f / (float)N_ROWS);
    out[OUT_AVG + t] = p;
    sP[t] = p * logf(p + 1e-10f);
    sL[t] = lossp[t];
    __syncthreads();
    for (int o = 512; o > 0; o >>= 1) {
        if (t < o) { sP[t] += sP[t + o]; sL[t] += sL[t + o]; }
        __syncthreads();
    }
    if (t == 0) {
        out[OUT_PPL] = expf(-sP[0]);
        out[OUT_LOSS] = 0.25f * (sL[0] * (1.0f / (float)(N_ROWS * C_DIM)));
    }
}

extern "C" void kernel_launch(void* const* d_in, const int* in_sizes, int n_in,
                              void* d_out, int out_size, void* d_ws, size_t ws_size,
                              hipStream_t stream) {
    const float* x = (const float*)d_in[0];
    const float* emb = (const float*)d_in[1];
    float* out = (float*)d_out;
    float* ws_f = (float*)d_ws;
    unsigned* ws_u = (unsigned*)d_ws;

    vq_prep<<<K_CODES / BLK, BLK, 0, stream>>>(emb, ws_f + WS_EE, ws_u + WS_HIST);

    vq_main<<<N_ROWS / RB, BLK, 0, stream>>>(x, emb, ws_f + WS_EE, ws_u + WS_HIST,
                                             ws_f + WS_LOSSP, out);

    vq_final<<<1, K_CODES, 0, stream>>>(ws_u + WS_HIST, ws_f + WS_LOSSP, out);
}

// Round 3
// 205.145 us; speedup vs baseline: 17.3991x; 17.3991x over previous
//
#include <hip/hip_runtime.h>
#include <math.h>
#include <float.h>

#define N_ROWS 65536
#define K_CODES 1024
#define C_DIM 64
#define KSPLIT 4
#define KPER (K_CODES / KSPLIT)   // 256 codes per split
#define BLK 256

typedef float f32x16 __attribute__((ext_vector_type(16)));

// d_out layout (float32), outputs concatenated in return order:
// [loss(1)][quantized_st(N*C)][perplexity(1)][indices(N)][avg_probs(K)]
#define OUT_LOSS 0
#define OUT_Q 1
#define OUT_PPL (1 + N_ROWS * C_DIM)     // 4194305
#define OUT_IDX (OUT_PPL + 1)            // 4194306
#define OUT_AVG (OUT_IDX + N_ROWS)       // 4259842

// d_ws layout (4-byte units)
#define WS_HIST 0                          // uint[1024]
#define WS_EE 1024                         // float[1024]
#define WS_LOSSP 2048                      // float[256] per-block loss partials
#define WS_PSCORE 2304                     // float[KSPLIT*N]
#define WS_PIDX (WS_PSCORE + KSPLIT * N_ROWS)  // int[KSPLIT*N]

// Kernel A: zero histogram, precompute ||e_k||^2
__global__ void vq_prep(const float* __restrict__ emb,
                        float* __restrict__ ee,
                        unsigned* __restrict__ hist) {
    int k = blockIdx.x * blockDim.x + threadIdx.x;
    if (k < K_CODES) {
        hist[k] = 0u;
        const float4* ev = (const float4*)(emb + (size_t)k * C_DIM);
        float s0 = 0.f, s1 = 0.f, s2 = 0.f, s3 = 0.f;
#pragma unroll
        for (int i = 0; i < 16; ++i) {
            float4 e = ev[i];
            s0 = fmaf(e.x, e.x, s0);
            s1 = fmaf(e.y, e.y, s1);
            s2 = fmaf(e.z, e.z, s2);
            s3 = fmaf(e.w, e.w, s3);
        }
        ee[k] = (s0 + s1) + (s2 + s3);
    }
}

// element c of the current code's row, c is compile-time constant
#define EV(c) ((c) < 16 ? e0[(c) & 15] : (c) < 32 ? e1[(c) & 15] \
               : (c) < 48 ? e2[(c) & 15] : e3[(c) & 15])

// Kernel B: lane-owns-row; codebook row is wave-uniform -> SGPR (s_load) stream.
// Per-lane x in VGPRs (16 float4). No LDS in the hot loop.
__global__ __launch_bounds__(BLK, 2) void vq_dist(
    const float* __restrict__ x, const float* __restrict__ emb,
    const float* __restrict__ ee,
    float* __restrict__ pscore, int* __restrict__ pidx) {
    const int row = blockIdx.x * BLK + threadIdx.x;
    const int k0 = blockIdx.y * KPER;

    // this lane's row into registers (row-contiguous; L1 absorbs line reuse)
    float4 xr[16];
    {
        const float4* xv = (const float4*)(x + (size_t)row * C_DIM);
#pragma unroll
        for (int i = 0; i < 16; ++i) xr[i] = xv[i];
    }

    float best = FLT_MAX;
    int bidx = 0;

    for (int k = k0; k < k0 + KPER; ++k) {
        // wave-uniform address: candidate for s_load_dwordx16 (SMEM pipe)
        const f32x16* ep = (const f32x16*)(emb + (size_t)k * C_DIM);
        f32x16 e0 = ep[0];
        f32x16 e1 = ep[1];
        f32x16 e2 = ep[2];
        f32x16 e3 = ep[3];
        float eek = ee[k];

        // exact summation order of the verified R1 kernel:
        // partials by c%4, ascending c, then (d0+d1)+(d2+d3)
        float d0 = 0.f, d1 = 0.f, d2 = 0.f, d3 = 0.f;
#pragma unroll
        for (int i = 0; i < 16; ++i) {
            float4 xi = xr[i];
            d0 = fmaf(xi.x, EV(4 * i + 0), d0);
            d1 = fmaf(xi.y, EV(4 * i + 1), d1);
            d2 = fmaf(xi.z, EV(4 * i + 2), d2);
            d3 = fmaf(xi.w, EV(4 * i + 3), d3);
        }
        float dot = (d0 + d1) + (d2 + d3);
        float s = fmaf(-2.0f, dot, eek);           // ||e||^2 - 2 x.e
        if (s < best) { best = s; bidx = k; }      // strict <: first-min wins
    }

    pscore[(size_t)blockIdx.y * N_ROWS + row] = best;
    pidx[(size_t)blockIdx.y * N_ROWS + row] = bidx;
}

// Kernel C: combine splits -> final index; histogram; coalesced epilogue
// (verbatim from the verified R1 kernel)
__global__ __launch_bounds__(BLK) void vq_combine(
    const float* __restrict__ x, const float* __restrict__ emb,
    const float* __restrict__ pscore, const int* __restrict__ pidx,
    unsigned* __restrict__ hist, float* __restrict__ lossp,
    float* __restrict__ out) {
    __shared__ int sIdx[BLK];
    __shared__ unsigned sHist[K_CODES];
    __shared__ float sRed[BLK / 64];

    const int t = threadIdx.x;
    const int base = blockIdx.x * BLK;

    for (int i = t; i < K_CODES; i += BLK) sHist[i] = 0u;

    // combine partial argmins (ascending split order preserves first-index ties)
    const int row = base + t;
    float best = pscore[row];
    int bidx = pidx[row];
#pragma unroll
    for (int s = 1; s < KSPLIT; ++s) {
        float sc = pscore[(size_t)s * N_ROWS + row];
        int id = pidx[(size_t)s * N_ROWS + row];
        if (sc < best) { best = sc; bidx = id; }
    }
    sIdx[t] = bidx;
    out[OUT_IDX + row] = (float)bidx;
    __syncthreads();  // sHist zero + sIdx visible
    atomicAdd(&sHist[bidx], 1u);
    __syncthreads();
    for (int i = t; i < K_CODES; i += BLK) {
        unsigned c = sHist[i];
        if (c) atomicAdd(&hist[i], c);
    }

    // epilogue: 4 rows per iteration, lane-coalesced over columns
    float lsum = 0.f;
    const int rl0 = t >> 6;  // 0..3 (wave id)
    const int col = t & 63;
    for (int it = 0; it < BLK / 4; ++it) {
        const int rl = it * 4 + rl0;
        const int r = base + rl;
        const int bi = sIdx[rl];  // uniform within wave -> LDS broadcast
        float xv = x[(size_t)r * C_DIM + col];
        float qv = emb[(size_t)bi * C_DIM + col];
        float d = qv - xv;
        out[OUT_Q + (size_t)r * C_DIM + col] = xv + d;  // straight-through
        lsum = fmaf(d, d, lsum);
    }

    // deterministic block reduction of loss partial
#pragma unroll
    for (int o = 32; o > 0; o >>= 1) lsum += __shfl_down(lsum, o, 64);
    if ((t & 63) == 0) sRed[t >> 6] = lsum;
    __syncthreads();
    if (t == 0) lossp[blockIdx.x] = (sRed[0] + sRed[1]) + (sRed[2] + sRed[3]);
}

// Kernel D: avg_probs, perplexity, loss finalization
__global__ void vq_final(const unsigned* __restrict__ hist,
                         const float* __restrict__ lossp,
                         float* __restrict__ out) {
    __shared__ float sP[K_CODES];
    __shared__ float sL[K_CODES];
    const int t = threadIdx.x;
    float p = (float)hist[t] * (1.0f / (float)N_ROWS);
    out[OUT_AVG + t] = p;
    sP[t] = p * logf(p + 1e-10f);
    sL[t] = (t < N_ROWS / BLK) ? lossp[t] : 0.f;
    __syncthreads();
    for (int o = 512; o > 0; o >>= 1) {
        if (t < o) { sP[t] += sP[t + o]; sL[t] += sL[t + o]; }
        __syncthreads();
    }
    if (t == 0) {
        out[OUT_PPL] = expf(-sP[0]);
        out[OUT_LOSS] = 0.25f * (sL[0] * (1.0f / (float)(N_ROWS * C_DIM)));
    }
}

extern "C" void kernel_launch(void* const* d_in, const int* in_sizes, int n_in,
                              void* d_out, int out_size, void* d_ws, size_t ws_size,
                              hipStream_t stream) {
    const float* x = (const float*)d_in[0];
    const float* emb = (const float*)d_in[1];
    float* out = (float*)d_out;
    float* ws_f = (float*)d_ws;
    unsigned* ws_u = (unsigned*)d_ws;
    int* ws_i = (int*)d_ws;

    vq_prep<<<K_CODES / BLK, BLK, 0, stream>>>(emb, ws_f + WS_EE, ws_u + WS_HIST);

    dim3 gB(N_ROWS / BLK, KSPLIT);
    vq_dist<<<gB, BLK, 0, stream>>>(x, emb, ws_f + WS_EE,
                                    ws_f + WS_PSCORE, ws_i + WS_PIDX);

    vq_combine<<<N_ROWS / BLK, BLK, 0, stream>>>(x, emb, ws_f + WS_PSCORE,
                                                 ws_i + WS_PIDX, ws_u + WS_HIST,
                                                 ws_f + WS_LOSSP, out);

    vq_final<<<1, K_CODES, 0, stream>>>(ws_u + WS_HIST, ws_f + WS_LOSSP, out);
}

// Round 4
// 181.854 us; speedup vs baseline: 19.6276x; 1.1281x over previous
//
#include <hip/hip_runtime.h>
#include <math.h>
#include <float.h>

#define N_ROWS 65536
#define K_CODES 1024
#define C_DIM 64
#define KSPLIT 8
#define KPER (K_CODES / KSPLIT)   // 128 codes per split
#define BLK 256

typedef float f32x16 __attribute__((ext_vector_type(16)));
typedef float f32x4v __attribute__((ext_vector_type(4)));

// d_out layout (float32), outputs concatenated in return order:
// [loss(1)][quantized_st(N*C)][perplexity(1)][indices(N)][avg_probs(K)]
#define OUT_LOSS 0
#define OUT_Q 1
#define OUT_PPL (1 + N_ROWS * C_DIM)     // 4194305
#define OUT_IDX (OUT_PPL + 1)            // 4194306
#define OUT_AVG (OUT_IDX + N_ROWS)       // 4259842

// d_ws layout (4-byte units)
#define WS_HIST 0          // uint[1024]
#define WS_EE 1024         // float[1024]
#define WS_LOSSP 2048      // float[256] per-block loss partials
#define WS_KEY 4096        // u64[N_ROWS] packed (score<<32 | idx), 8B-aligned

// Kernel A: zero histogram, precompute ||e_k||^2
__global__ void vq_prep(const float* __restrict__ emb,
                        float* __restrict__ ee,
                        unsigned* __restrict__ hist) {
    int k = blockIdx.x * blockDim.x + threadIdx.x;
    if (k < K_CODES) {
        hist[k] = 0u;
        const float4* ev = (const float4*)(emb + (size_t)k * C_DIM);
        float s0 = 0.f, s1 = 0.f, s2 = 0.f, s3 = 0.f;
#pragma unroll
        for (int i = 0; i < 16; ++i) {
            float4 e = ev[i];
            s0 = fmaf(e.x, e.x, s0);
            s1 = fmaf(e.y, e.y, s1);
            s2 = fmaf(e.z, e.z, s2);
            s3 = fmaf(e.w, e.w, s3);
        }
        ee[k] = (s0 + s1) + (s2 + s3);
    }
}

// element c of the current code's row, c is compile-time constant
#define EV(c) ((c) < 16 ? e0[(c) & 15] : (c) < 32 ? e1[(c) & 15] \
               : (c) < 48 ? e2[(c) & 15] : e3[(c) & 15])

// Kernel B: lane-owns-row; codebook row wave-uniform -> SGPR (s_load) stream.
// x pinned in VGPRs via opaque asm (prevents rematerialization of the loads).
// Result merged via packed u64 atomicMin: exact first-min argmin semantics.
__global__ __launch_bounds__(BLK, 4) void vq_dist(
    const float* __restrict__ x, const float* __restrict__ emb,
    const float* __restrict__ ee,
    unsigned long long* __restrict__ keys) {
    const int row = blockIdx.x * BLK + threadIdx.x;
    const int k0 = blockIdx.y * KPER;

    // this lane's row into registers, then pin (asm-defined values can't be
    // rematerialized from memory by the register allocator)
    f32x4v xr[16];
    {
        const f32x4v* xv = (const f32x4v*)(x + (size_t)row * C_DIM);
#pragma unroll
        for (int i = 0; i < 16; ++i) xr[i] = xv[i];
#pragma unroll
        for (int i = 0; i < 16; ++i) asm volatile("" : "+v"(xr[i]));
    }

    float best = FLT_MAX;
    int bidx = 0;

    for (int k = k0; k < k0 + KPER; ++k) {
        // wave-uniform address -> s_load_dwordx16 (SMEM pipe)
        const f32x16* ep = (const f32x16*)(emb + (size_t)k * C_DIM);
        f32x16 e0 = ep[0];
        f32x16 e1 = ep[1];
        f32x16 e2 = ep[2];
        f32x16 e3 = ep[3];
        float eek = ee[k];

        // exact summation order of the verified kernels:
        // partials by c%4, ascending c, then (d0+d1)+(d2+d3)
        float d0 = 0.f, d1 = 0.f, d2 = 0.f, d3 = 0.f;
#pragma unroll
        for (int i = 0; i < 16; ++i) {
            d0 = fmaf(xr[i][0], EV(4 * i + 0), d0);
            d1 = fmaf(xr[i][1], EV(4 * i + 1), d1);
            d2 = fmaf(xr[i][2], EV(4 * i + 2), d2);
            d3 = fmaf(xr[i][3], EV(4 * i + 3), d3);
        }
        float dot = (d0 + d1) + (d2 + d3);
        float s = fmaf(-2.0f, dot, eek);           // ||e||^2 - 2 x.e
        if (s < best) { best = s; bidx = k; }      // strict <: first-min in strip
    }

    // monotone f32 -> u32 map (order-preserving, no NaN here), pack with idx.
    // min(key) == (min score, then min idx) == numpy first-min argmin.
    unsigned sb = __float_as_uint(best);
    sb = (sb & 0x80000000u) ? ~sb : (sb | 0x80000000u);
    unsigned long long key = ((unsigned long long)sb << 32) | (unsigned)bidx;
    atomicMin(&keys[row], key);
}

// Kernel C: extract index; histogram; coalesced epilogue
__global__ __launch_bounds__(BLK) void vq_combine(
    const float* __restrict__ x, const float* __restrict__ emb,
    const unsigned long long* __restrict__ keys,
    unsigned* __restrict__ hist, float* __restrict__ lossp,
    float* __restrict__ out) {
    __shared__ int sIdx[BLK];
    __shared__ unsigned sHist[K_CODES];
    __shared__ float sRed[BLK / 64];

    const int t = threadIdx.x;
    const int base = blockIdx.x * BLK;

    for (int i = t; i < K_CODES; i += BLK) sHist[i] = 0u;

    const int row = base + t;
    const int bidx = (int)(unsigned)(keys[row] & 0xFFFFFFFFull);
    sIdx[t] = bidx;
    out[OUT_IDX + row] = (float)bidx;
    __syncthreads();  // sHist zero + sIdx visible
    atomicAdd(&sHist[bidx], 1u);
    __syncthreads();
    for (int i = t; i < K_CODES; i += BLK) {
        unsigned c = sHist[i];
        if (c) atomicAdd(&hist[i], c);
    }

    // epilogue: 4 rows per iteration, lane-coalesced over columns
    float lsum = 0.f;
    const int rl0 = t >> 6;  // 0..3 (wave id)
    const int col = t & 63;
    for (int it = 0; it < BLK / 4; ++it) {
        const int rl = it * 4 + rl0;
        const int r = base + rl;
        const int bi = sIdx[rl];  // uniform within wave -> LDS broadcast
        float xv = x[(size_t)r * C_DIM + col];
        float qv = emb[(size_t)bi * C_DIM + col];
        float d = qv - xv;
        out[OUT_Q + (size_t)r * C_DIM + col] = xv + d;  // straight-through
        lsum = fmaf(d, d, lsum);
    }

    // deterministic block reduction of loss partial
#pragma unroll
    for (int o = 32; o > 0; o >>= 1) lsum += __shfl_down(lsum, o, 64);
    if ((t & 63) == 0) sRed[t >> 6] = lsum;
    __syncthreads();
    if (t == 0) lossp[blockIdx.x] = (sRed[0] + sRed[1]) + (sRed[2] + sRed[3]);
}

// Kernel D: avg_probs, perplexity, loss finalization
__global__ void vq_final(const unsigned* __restrict__ hist,
                         const float* __restrict__ lossp,
                         float* __restrict__ out) {
    __shared__ float sP[K_CODES];
    __shared__ float sL[K_CODES];
    const int t = threadIdx.x;
    float p = (float)hist[t] * (1.0f / (float)N_ROWS);
    out[OUT_AVG + t] = p;
    sP[t] = p * logf(p + 1e-10f);
    sL[t] = (t < N_ROWS / BLK) ? lossp[t] : 0.f;
    __syncthreads();
    for (int o = 512; o > 0; o >>= 1) {
        if (t < o) { sP[t] += sP[t + o]; sL[t] += sL[t + o]; }
        __syncthreads();
    }
    if (t == 0) {
        out[OUT_PPL] = expf(-sP[0]);
        out[OUT_LOSS] = 0.25f * (sL[0] * (1.0f / (float)(N_ROWS * C_DIM)));
    }
}

extern "C" void kernel_launch(void* const* d_in, const int* in_sizes, int n_in,
                              void* d_out, int out_size, void* d_ws, size_t ws_size,
                              hipStream_t stream) {
    const float* x = (const float*)d_in[0];
    const float* emb = (const float*)d_in[1];
    float* out = (float*)d_out;
    float* ws_f = (float*)d_ws;
    unsigned* ws_u = (unsigned*)d_ws;
    unsigned long long* keys = (unsigned long long*)(ws_u + WS_KEY);

    // keys := +inf pattern (0xFF..) every call — replay-safe
    hipMemsetAsync(keys, 0xFF, (size_t)N_ROWS * sizeof(unsigned long long), stream);

    vq_prep<<<K_CODES / BLK, BLK, 0, stream>>>(emb, ws_f + WS_EE, ws_u + WS_HIST);

    dim3 gB(N_ROWS / BLK, KSPLIT);
    vq_dist<<<gB, BLK, 0, stream>>>(x, emb, ws_f + WS_EE, keys);

    vq_combine<<<N_ROWS / BLK, BLK, 0, stream>>>(x, emb, keys, ws_u + WS_HIST,
                                                 ws_f + WS_LOSSP, out);

    vq_final<<<1, K_CODES, 0, stream>>>(ws_u + WS_HIST, ws_f + WS_LOSSP, out);
}